// Round 9
// baseline (169.710 us; speedup 1.0000x reference)
//
#include <hip/hip_runtime.h>
#include <stdint.h>

constexpr int T_TOK = 8192;
constexpr int D_DIM = 1024;
constexpr int H_DIM = 2048;
constexpr int E_NUM = 8;

typedef __bf16 bf16x8 __attribute__((ext_vector_type(8)));
typedef float  f32x4  __attribute__((ext_vector_type(4)));

static __device__ __forceinline__ unsigned short f2bf(float f) {
  union { float f; unsigned u; } a; a.f = f;
  unsigned r = a.u + 0x7fffu + ((a.u >> 16) & 1u);   // RNE
  return (unsigned short)(r >> 16);
}

// ---------------- fp32 -> bf16 conversion (x only) ----------------
__global__ void cvt_f32_bf16(const float* __restrict__ src,
                             unsigned short* __restrict__ dst, int n4) {
  int i = blockIdx.x * blockDim.x + threadIdx.x;
  int stride = gridDim.x * blockDim.x;
  for (; i < n4; i += stride) {
    float4 v = reinterpret_cast<const float4*>(src)[i];
    ushort4 o;
    o.x = f2bf(v.x); o.y = f2bf(v.y); o.z = f2bf(v.z); o.w = f2bf(v.w);
    reinterpret_cast<ushort4*>(dst)[i] = o;
  }
}

#define FENCE() asm volatile("" ::: "memory")
#define BARRIER() do { FENCE(); __builtin_amdgcn_s_barrier(); FENCE(); } while (0)
#define WAIT_VM(N) asm volatile("s_waitcnt vmcnt(%0)" :: "i"(N) : "memory")
#define SCHED_FENCE() __builtin_amdgcn_sched_barrier(0)

static __device__ __forceinline__ f32x4 gload4(const void* p) {
  f32x4 r;
  asm volatile("global_load_dwordx4 %0, %1, off" : "=v"(r) : "v"(p) : "memory");
  return r;
}

// ---- grouped GEMM: A via LDS dbuf (gload_lds), B fp32 DIRECT-TO-REG ----
// BM=256, BN=128, BK=64, 8 waves (2wr x 4wc). One barrier + two vm-waits
// per K-tile. B fragments are per-lane row-chunks of row-major (N,K) fp32
// weights: lane loads its own 32B (2 x dwordx4, wave = 16 x 64B lines),
// converts in-reg, feeds MFMA. No B LDS, no ds_write, no write swizzle.
//
// vmcnt FIFO (per wave, steady state; iter-top outstanding = [B_t(8)]):
//   stageA(4) + loadB_{t+1}(8)       -> [B_t8, A4, B8]
//   WAIT_VM(12) drains B_t -> cvt    -> [A4, B8]
//   WAIT_VM(8)  drains A   -> BARRIER-> [B8]
// Post-loop: WAIT_VM(0) + keep-alive on bq regs (round-6 writeback hazard).
template <int K_DIM, int N_DIM, bool RELU2>
__global__ __launch_bounds__(512, 2)
void gg9(const unsigned short* __restrict__ A,
         const float* __restrict__ Bw,
         const int* __restrict__ counts,
         void* __restrict__ Cout) {
  constexpr int BM = 256, BN = 128, BK = 64;
  constexpr int NT = K_DIM / BK;
  constexpr int NACC = 2;              // n-frags per wave (32 cols)

  const int tid  = threadIdx.x;
  const int wid  = tid >> 6;
  const int lane = tid & 63;
  const int wr   = wid >> 2;           // 0..1
  const int wc   = wid & 3;            // 0..3

  // ---- blockIdx.x -> (expert, 256-row tile)
  int t = blockIdx.x;
  int e = -1, rowBase = 0, rowsValid = 0;
  {
    int tiles = 0, off = 0;
#pragma unroll
    for (int i = 0; i < E_NUM; ++i) {
      int n  = counts[i];
      int nt = (n + BM - 1) / BM;
      if (e < 0 && t < tiles + nt) {
        e = i;
        int lt = t - tiles;
        rowBase   = off + lt * BM;
        rowsValid = n - lt * BM;
        if (rowsValid > BM) rowsValid = BM;
      }
      tiles += nt; off += n;
    }
  }
  if (e < 0) return;
  const int colBase = blockIdx.y * BN;

  __shared__ __align__(1024) char lds[2 * BM * 128];   // A dbuf, 64 KiB
  auto ldsA = [&](int b) -> char* { return lds + b * (BM * 128); };

  const char* gA = (const char*)A + (size_t)rowBase * (K_DIM * 2);

  const int lr8 = lane >> 3;
  const int gsw = (lane & 7) ^ lr8;    // inverse-swizzled source granule (A)

  auto stageA = [&](int buf, int alpha, int kt) {
#pragma unroll
    for (int j = 0; j < 2; ++j) {
      int bi   = j * 8 + wid;
      int row0 = (bi >> 3) * 128 + alpha * 64 + (bi & 7) * 8;
      int sr   = row0 + lr8;
      if (sr >= rowsValid) sr = rowsValid - 1;
      const char* src = gA + (size_t)sr * (K_DIM * 2) + (size_t)kt * 128 + gsw * 16;
      __builtin_amdgcn_global_load_lds(
          (const __attribute__((address_space(1))) void*)src,
          (__attribute__((address_space(3))) void*)(ldsA(buf) + row0 * 128),
          16, 0, 0);
    }
  };

  const int rowLane = lane & 15;
  const int grpA    = lane >> 4;       // 0..3 (k-granule)
  const int swzm    = lane & 7;

  // B per-lane fragment bases: row = colBase + wc*32 + n*16 + rowLane
  const char* gBrow[NACC];
#pragma unroll
  for (int n = 0; n < NACC; ++n)
    gBrow[n] = (const char*)Bw +
        ((size_t)e * N_DIM + colBase + wc * 32 + n * 16 + rowLane) * (size_t)(K_DIM * 4)
        + (size_t)grpA * 32;

  // load the 8 fp32x4 for one K-tile: frag (n,ks) <- q[n*4+ks*2+{0,1}]
  auto loadB = [&](f32x4 (&q)[8], int kt) {
#pragma unroll
    for (int n = 0; n < NACC; ++n)
#pragma unroll
      for (int ks = 0; ks < 2; ++ks) {
        const char* s = gBrow[n] + (size_t)kt * 256 + ks * 128;
        q[n * 4 + ks * 2 + 0] = gload4(s);
        q[n * 4 + ks * 2 + 1] = gload4(s + 16);
      }
  };
  auto cvtB = [&](const f32x4 (&q)[8], int ks, bf16x8 (&bF)[NACC]) {
#pragma unroll
    for (int n = 0; n < NACC; ++n) {
      union { __bf16 b[8]; bf16x8 v; } u;
#pragma unroll
      for (int j = 0; j < 2; ++j)
#pragma unroll
        for (int p = 0; p < 4; ++p)
          u.b[j * 4 + p] = (__bf16)q[n * 4 + ks * 2 + j][p];
      bF[n] = u.v;
    }
  };

  f32x4 accC[8][NACC];
#pragma unroll
  for (int m = 0; m < 8; ++m)
#pragma unroll
    for (int n = 0; n < NACC; ++n) accC[m][n] = (f32x4){0.f, 0.f, 0.f, 0.f};

  // read the 8 A-frags for one ks half (row = wr*128 + m*16 + rowLane)
  auto readAks = [&](int buf, int ks, bf16x8 (&aF)[8]) {
    const char* base = ldsA(buf) + (wr * 128 + rowLane) * 128;
#pragma unroll
    for (int m = 0; m < 8; ++m) {
      int g = (ks * 4 + grpA) ^ swzm;
      aF[m] = *(const bf16x8*)(base + m * (16 * 128) + g * 16);
    }
  };

  f32x4 bqA[8], bqB[8];
  bf16x8 aF[8], bF[NACC];

  // ---- prologue: A(0) -> buf0, B(0) -> bqA; fully drained
  stageA(0, 0, 0); stageA(0, 1, 0);
  SCHED_FENCE();
  loadB(bqA, 0);
  WAIT_VM(0);
  SCHED_FENCE();
  BARRIER();

#define ITER(T, CUR, BQC, BQN)                                                \
  do {                                                                        \
    const int ktn_ = ((T) + 1 < NT) ? (T) + 1 : NT - 1;                       \
    stageA((CUR) ^ 1, 0, ktn_);                                               \
    stageA((CUR) ^ 1, 1, ktn_);                                               \
    SCHED_FENCE();                                                            \
    loadB(BQN, ktn_);                                                         \
    readAks(CUR, 0, aF);                                                      \
    WAIT_VM(12);                                                              \
    SCHED_FENCE();                                                            \
    cvtB(BQC, 0, bF);                                                         \
    __builtin_amdgcn_s_setprio(1);                                            \
    _Pragma("unroll")                                                         \
    for (int m_ = 0; m_ < 8; ++m_)                                            \
      _Pragma("unroll")                                                       \
      for (int n_ = 0; n_ < NACC; ++n_)                                       \
        accC[m_][n_] = __builtin_amdgcn_mfma_f32_16x16x32_bf16(               \
            aF[m_], bF[n_], accC[m_][n_], 0, 0, 0);                           \
    __builtin_amdgcn_s_setprio(0);                                            \
    readAks(CUR, 1, aF);                                                      \
    cvtB(BQC, 1, bF);                                                         \
    __builtin_amdgcn_s_setprio(1);                                            \
    _Pragma("unroll")                                                         \
    for (int m_ = 0; m_ < 8; ++m_)                                            \
      _Pragma("unroll")                                                       \
      for (int n_ = 0; n_ < NACC; ++n_)                                       \
        accC[m_][n_] = __builtin_amdgcn_mfma_f32_16x16x32_bf16(               \
            aF[m_], bF[n_], accC[m_][n_], 0, 0, 0);                           \
    __builtin_amdgcn_s_setprio(0);                                            \
    WAIT_VM(8);                                                               \
    BARRIER();                                                                \
  } while (0)

  for (int t2 = 0; t2 < NT; t2 += 2) {
    ITER(t2,     0, bqA, bqB);
    ITER(t2 + 1, 1, bqB, bqA);
  }
#undef ITER

  // ---- drain never-consumed final loads; keep dest regs alive (r6 lesson)
  WAIT_VM(0);
  SCHED_FENCE();
#pragma unroll
  for (int j = 0; j < 8; ++j) {
    asm volatile("" :: "v"(bqA[j]), "v"(bqB[j]));
  }

  // ---- epilogue. C/D: col = lane&15, row = (lane>>4)*4 + j
  const int rB0 = wr * 128 + grpA * 4;
  const int cB0 = colBase + wc * 32 + rowLane;
#pragma unroll
  for (int m = 0; m < 8; ++m) {
#pragma unroll
    for (int n = 0; n < NACC; ++n) {
#pragma unroll
      for (int j = 0; j < 4; ++j) {
        int r = rB0 + m * 16 + j;
        if (r < rowsValid) {
          size_t idx = (size_t)(rowBase + r) * N_DIM + (cB0 + n * 16);
          float v = accC[m][n][j];
          if (RELU2) {
            float rl = v > 0.f ? v : 0.f;
            float hf = (float)(__bf16)rl;              // bf16(relu(acc))
            ((__bf16*)Cout)[idx] = (__bf16)(hf * hf);  // bf16 square
          } else {
            ((float*)Cout)[idx] = (float)(__bf16)v;    // float(bf16(acc))
          }
        }
      }
    }
  }
}

extern "C" void kernel_launch(void* const* d_in, const int* in_sizes, int n_in,
                              void* d_out, int out_size, void* d_ws, size_t ws_size,
                              hipStream_t stream) {
  const float* x   = (const float*)d_in[0];
  const int*   cnt = (const int*)d_in[1];
  const float* wu  = (const float*)d_in[2];
  const float* wd  = (const float*)d_in[3];
  float* out = (float*)d_out;
  char*  ws  = (char*)d_ws;

  unsigned short* xb   = (unsigned short*)(ws);                // 16 MiB
  unsigned short* hbuf = (unsigned short*)(ws + (16u << 20));  // 32 MiB

  cvt_f32_bf16<<<2048, 256, 0, stream>>>(x, xb, T_TOK * D_DIM / 4);

  // grid.x = max row tiles: floor(T/256) + E = 40 (excess blocks exit early)
  gg9<D_DIM, H_DIM, true ><<<dim3(40, H_DIM / 128), dim3(512), 0, stream>>>(
      xb, wu, cnt, (void*)hbuf);
  gg9<H_DIM, D_DIM, false><<<dim3(40, D_DIM / 128), dim3(512), 0, stream>>>(
      hbuf, wd, cnt, (void*)out);
}

// Round 10
// 150.232 us; speedup vs baseline: 1.1296x; 1.1296x over previous
//
#include <hip/hip_runtime.h>
#include <stdint.h>

constexpr int T_TOK = 8192;
constexpr int D_DIM = 1024;
constexpr int H_DIM = 2048;
constexpr int E_NUM = 8;
constexpr int CVX   = 27;   // extra grid.x blocks in GEMM1 for w_down convert

typedef __bf16 bf16x8 __attribute__((ext_vector_type(8)));
typedef float  f32x4  __attribute__((ext_vector_type(4)));
typedef unsigned int u32x4 __attribute__((ext_vector_type(4)));

static __device__ __forceinline__ unsigned short f2bf(float f) {
  union { float f; unsigned u; } a; a.f = f;
  unsigned r = a.u + 0x7fffu + ((a.u >> 16) & 1u);   // RNE
  return (unsigned short)(r >> 16);
}

// ---------------- fp32 -> bf16 conversion (x only) ----------------
__global__ void cvt_f32_bf16(const float* __restrict__ src,
                             unsigned short* __restrict__ dst, int n4) {
  int i = blockIdx.x * blockDim.x + threadIdx.x;
  int stride = gridDim.x * blockDim.x;
  for (; i < n4; i += stride) {
    float4 v = reinterpret_cast<const float4*>(src)[i];
    ushort4 o;
    o.x = f2bf(v.x); o.y = f2bf(v.y); o.z = f2bf(v.z); o.w = f2bf(v.w);
    reinterpret_cast<ushort4*>(dst)[i] = o;
  }
}

#define FENCE() asm volatile("" ::: "memory")
#define BARRIER() do { FENCE(); __builtin_amdgcn_s_barrier(); FENCE(); } while (0)
#define WAIT_LGKM0() asm volatile("s_waitcnt lgkmcnt(0)" ::: "memory")
#define WAIT_VM(N) asm volatile("s_waitcnt vmcnt(%0)" :: "i"(N) : "memory")
#define SCHED_FENCE() __builtin_amdgcn_sched_barrier(0)

static __device__ __forceinline__ f32x4 gload4(const void* p) {
  f32x4 r;
  asm volatile("global_load_dwordx4 %0, %1, off" : "=v"(r) : "v"(p) : "memory");
  return r;
}

// ============ GEMM1: fused w_up fp32->bf16 (round-8 4-phase, BN=256) ============
// Extra blocks (blockIdx.x >= 40) convert w_down fp32->bf16 into workspace,
// co-resident with the GEMM blocks (zero LDS, low VGPR -> free wave slots).
__global__ __launch_bounds__(512, 2)
void gg1(const unsigned short* __restrict__ A,
         const float* __restrict__ Bw,
         const int* __restrict__ counts,
         unsigned short* __restrict__ Hout,
         const float* __restrict__ cvsrc,
         unsigned short* __restrict__ cvdst) {
  constexpr int K_DIM = D_DIM, N_DIM = H_DIM;
  constexpr int BM = 256, BK = 64, BN = 256;
  constexpr int NT = K_DIM / BK;
  constexpr int WNC = 64, NACC = 4, NQN = 2, BL = 4, TSH = 2, FPB = 64;

  const int tid = threadIdx.x;

  // ---- co-scheduled w_down converter ----
  if (blockIdx.x >= 40) {
    const int cid = (blockIdx.x - 40) * 8 + blockIdx.y;   // gridDim.y == 8
    constexpr int CVN4  = E_NUM * D_DIM * H_DIM / 4;      // 4,194,304 float4
    constexpr int CVSTR = CVX * 8 * 512;
    for (int i = cid * 512 + tid; i < CVN4; i += CVSTR) {
      float4 v = reinterpret_cast<const float4*>(cvsrc)[i];
      ushort4 o;
      o.x = f2bf(v.x); o.y = f2bf(v.y); o.z = f2bf(v.z); o.w = f2bf(v.w);
      reinterpret_cast<ushort4*>(cvdst)[i] = o;
    }
    return;
  }

  const int wid  = tid >> 6;
  const int lane = tid & 63;
  const int wr   = wid >> 2;
  const int wc   = wid & 3;

  // ---- blockIdx.x -> (expert, 256-row tile)
  int t = blockIdx.x;
  int e = -1, rowBase = 0, rowsValid = 0;
  {
    int tiles = 0, off = 0;
#pragma unroll
    for (int i = 0; i < E_NUM; ++i) {
      int n  = counts[i];
      int nt = (n + BM - 1) / BM;
      if (e < 0 && t < tiles + nt) {
        e = i;
        int lt = t - tiles;
        rowBase   = off + lt * BM;
        rowsValid = n - lt * BM;
        if (rowsValid > BM) rowsValid = BM;
      }
      tiles += nt; off += n;
    }
  }
  if (e < 0) return;
  const int colBase = blockIdx.y * BN;

  __shared__ __align__(1024) char lds[(BM + BN) * BK * 2 * 2];  // 128 KiB
  auto ldsA = [&](int b) -> char* { return lds + b * (BM * 128); };
  auto ldsB = [&](int b) -> char* { return lds + 2 * (BM * 128) + b * (BN * 128); };

  const char* gA = (const char*)A + (size_t)rowBase * (K_DIM * 2);
  const int  bRow0 = tid >> TSH;
  const int  bByte = (tid & ((1 << TSH) - 1)) * FPB;
  const char* gBbase = (const char*)Bw +
      ((size_t)e * N_DIM + colBase) * (size_t)(K_DIM * 4);

  const int lr8 = lane >> 3;
  const int gsw = (lane & 7) ^ lr8;

  auto stageA = [&](int buf, int alpha, int kt) {
#pragma unroll
    for (int j = 0; j < 2; ++j) {
      int bi   = j * 8 + wid;
      int row0 = (bi >> 3) * 128 + alpha * 64 + (bi & 7) * 8;
      int sr   = row0 + lr8;
      if (sr >= rowsValid) sr = rowsValid - 1;
      const char* src = gA + (size_t)sr * (K_DIM * 2) + (size_t)kt * 128 + gsw * 16;
      __builtin_amdgcn_global_load_lds(
          (const __attribute__((address_space(1))) void*)src,
          (__attribute__((address_space(3))) void*)(ldsA(buf) + row0 * 128),
          16, 0, 0);
    }
  };

  auto loadBhalf = [&](f32x4 (&q)[BL], int h, int kt) {
    const char* s = gBbase + (size_t)(h * (BN / 2) + bRow0) * (K_DIM * 4)
                  + (size_t)kt * 256 + bByte;
#pragma unroll
    for (int j = 0; j < BL; ++j) q[j] = gload4(s + j * 16);
  };
  auto writeBhalf = [&](int buf, const f32x4 (&q)[BL], int h) {
    const int row = h * (BN / 2) + bRow0;
    char* base = ldsB(buf) + row * 128;
    const int rs = row & 7;
#pragma unroll
    for (int c = 0; c < BL / 2; ++c) {
      union { __bf16 b[8]; u32x4 w; } u;
#pragma unroll
      for (int k = 0; k < 2; ++k)
#pragma unroll
        for (int p = 0; p < 4; ++p)
          u.b[k * 4 + p] = (__bf16)q[c * 2 + k][p];
      int g = 2 * (tid & 3) + c;
      *reinterpret_cast<u32x4*>(base + (g ^ rs) * 16) = u.w;
    }
  };

  const int rowLane = lane & 15;
  const int grpA    = lane >> 4;
  const int swzm    = lane & 7;

  bf16x8 aF[4][2];
  f32x4  accC[8][NACC];
#pragma unroll
  for (int m = 0; m < 8; ++m)
#pragma unroll
    for (int n = 0; n < NACC; ++n) accC[m][n] = (f32x4){0.f, 0.f, 0.f, 0.f};

  auto readA = [&](int buf, int rh) {
    const char* base = ldsA(buf) + (wr * 128 + rh * 64 + rowLane) * 128;
#pragma unroll
    for (int m = 0; m < 4; ++m)
#pragma unroll
      for (int ks = 0; ks < 2; ++ks) {
        int g = (ks * 4 + grpA) ^ swzm;
        aF[m][ks] = *(const bf16x8*)(base + m * (16 * 128) + g * 16);
      }
  };
  bf16x8 bF0[NQN][2], bF1[NQN][2];
  auto readB = [&](int buf, int ch, bf16x8 (&dst)[NQN][2]) {
    const char* base = ldsB(buf) + (wc * WNC + ch * (WNC / 2) + rowLane) * 128;
#pragma unroll
    for (int n = 0; n < NQN; ++n)
#pragma unroll
      for (int ks = 0; ks < 2; ++ks) {
        int g = (ks * 4 + grpA) ^ swzm;
        dst[n][ks] = *(const bf16x8*)(base + n * (16 * 128) + g * 16);
      }
  };

#define MFMAQ(RH, CH, BFA)                                                    \
  do {                                                                        \
    __builtin_amdgcn_s_setprio(1);                                            \
    _Pragma("unroll")                                                         \
    for (int m_ = 0; m_ < 4; ++m_) {                                          \
      _Pragma("unroll")                                                       \
      for (int n_ = 0; n_ < NQN; ++n_) {                                      \
        f32x4 c_ = accC[(RH) * 4 + m_][(CH) * NQN + n_];                      \
        c_ = __builtin_amdgcn_mfma_f32_16x16x32_bf16(aF[m_][0], BFA[n_][0], c_, 0, 0, 0); \
        c_ = __builtin_amdgcn_mfma_f32_16x16x32_bf16(aF[m_][1], BFA[n_][1], c_, 0, 0, 0); \
        accC[(RH) * 4 + m_][(CH) * NQN + n_] = c_;                            \
      }                                                                       \
    }                                                                         \
    __builtin_amdgcn_s_setprio(0);                                            \
  } while (0)

  f32x4 bq0[BL], bq1[BL];

  // ---- prologue: tile0 -> buf0; leave tile1 B loads in flight (2BL)
  loadBhalf(bq0, 0, 0);
  loadBhalf(bq1, 1, 0);
  stageA(0, 0, 0); stageA(0, 1, 0);
  WAIT_VM(BL + 4); SCHED_FENCE();
  writeBhalf(0, bq0, 0);
  loadBhalf(bq0, 0, 1);
  WAIT_VM(BL + 4); SCHED_FENCE();
  writeBhalf(0, bq1, 1);
  loadBhalf(bq1, 1, 1);
  WAIT_VM(2 * BL);
  WAIT_LGKM0();
  BARRIER();

  for (int t2 = 0; t2 < NT; ++t2) {
    const int cur = t2 & 1, nxt = cur ^ 1;
    const int ktn  = (t2 + 1 < NT) ? t2 + 1 : NT - 1;
    const int ktn2 = (t2 + 2 < NT) ? t2 + 2 : NT - 1;

    // P1
    stageA(nxt, 0, ktn);
    stageA(nxt, 1, ktn);
    readA(cur, 0); readB(cur, 0, bF0);
    BARRIER(); WAIT_LGKM0();
    MFMAQ(0, 0, bF0);
    BARRIER();
    // P2
    readB(cur, 1, bF1);
    BARRIER(); WAIT_LGKM0();
    MFMAQ(0, 1, bF1);
    BARRIER();
    // P3
    WAIT_VM(BL + 4);
    SCHED_FENCE();
    writeBhalf(nxt, bq0, 0);
    loadBhalf(bq0, 0, ktn2);
    readA(cur, 1);
    BARRIER(); WAIT_LGKM0();
    MFMAQ(1, 1, bF1);
    BARRIER();
    // P4
    WAIT_VM(BL + 4);
    SCHED_FENCE();
    writeBhalf(nxt, bq1, 1);
    loadBhalf(bq1, 1, ktn2);
    WAIT_VM(2 * BL);
    BARRIER(); WAIT_LGKM0();
    MFMAQ(1, 0, bF0);
    BARRIER();
  }
#undef MFMAQ

  // ---- drain never-consumed reloads; keep dest regs alive (r6 lesson)
  WAIT_VM(0);
  SCHED_FENCE();
#pragma unroll
  for (int j = 0; j < BL; ++j) {
    asm volatile("" :: "v"(bq0[j]), "v"(bq1[j]));
  }

  // ---- epilogue: h = bf16(bf16(relu(acc))^2)
  const int rB0 = wr * 128 + grpA * 4;
  const int cB0 = colBase + wc * WNC + rowLane;
#pragma unroll
  for (int m = 0; m < 8; ++m) {
#pragma unroll
    for (int n = 0; n < NACC; ++n) {
#pragma unroll
      for (int j = 0; j < 4; ++j) {
        int r = rB0 + m * 16 + j;
        if (r < rowsValid) {
          size_t idx = (size_t)(rowBase + r) * N_DIM + (cB0 + n * 16);
          float v = accC[m][n][j];
          float rl = v > 0.f ? v : 0.f;
          float hf = (float)(__bf16)rl;
          ((__bf16*)Hout)[idx] = (__bf16)(hf * hf);
        }
      }
    }
  }
}

// ============ GEMM2: round-2-proven clean bf16 B (gload_lds), BN=128 ============
template <int K_DIM, int N_DIM>
__global__ __launch_bounds__(512, 2)
void gg2(const unsigned short* __restrict__ A,
         const unsigned short* __restrict__ Bw,
         const int* __restrict__ counts,
         float* __restrict__ Cout) {
  constexpr int BM = 256, BK = 64, BN = 128;
  constexpr int NT = K_DIM / BK;
  constexpr int NITER = NT / 2;
  constexpr int WNC = 32, VN = 5;

  const int tid  = threadIdx.x;
  const int wid  = tid >> 6;
  const int lane = tid & 63;
  const int wr   = wid >> 2;
  const int wc   = wid & 3;

  int t = blockIdx.x;
  int e = -1, rowBase = 0, rowsValid = 0;
  {
    int tiles = 0, off = 0;
#pragma unroll
    for (int i = 0; i < E_NUM; ++i) {
      int n  = counts[i];
      int nt = (n + BM - 1) / BM;
      if (e < 0 && t < tiles + nt) {
        e = i;
        int lt = t - tiles;
        rowBase   = off + lt * BM;
        rowsValid = n - lt * BM;
        if (rowsValid > BM) rowsValid = BM;
      }
      tiles += nt; off += n;
    }
  }
  if (e < 0) return;
  const int colBase = blockIdx.y * BN;

  __shared__ __align__(1024) char lds[(BM + BN) * BK * 2 * 2];  // 96 KiB
  auto ldsA = [&](int b) -> char* { return lds + b * (BM * 128); };
  auto ldsB = [&](int b) -> char* { return lds + 2 * (BM * 128) + b * (BN * 128); };

  const char* gA = (const char*)A + (size_t)rowBase * (K_DIM * 2);
  const char* gB = (const char*)Bw + ((size_t)e * N_DIM + colBase) * (size_t)(K_DIM * 2);

  const int lr8 = lane >> 3;
  const int gsw = (lane & 7) ^ lr8;

  auto stageA = [&](int buf, int alpha, int kt) {
#pragma unroll
    for (int j = 0; j < 2; ++j) {
      int bi   = j * 8 + wid;
      int row0 = (bi >> 3) * 128 + alpha * 64 + (bi & 7) * 8;
      int sr   = row0 + lr8;
      if (sr >= rowsValid) sr = rowsValid - 1;
      const char* src = gA + (size_t)sr * (K_DIM * 2) + (size_t)kt * 128 + gsw * 16;
      __builtin_amdgcn_global_load_lds(
          (const __attribute__((address_space(1))) void*)src,
          (__attribute__((address_space(3))) void*)(ldsA(buf) + row0 * 128),
          16, 0, 0);
    }
  };
  auto stageB = [&](int buf, int alpha, int kt) {
    int bi   = wid;
    int row0 = (bi >> 1) * 32 + alpha * 16 + (bi & 1) * 8;
    int sr   = row0 + lr8;
    const char* src = gB + (size_t)sr * (K_DIM * 2) + (size_t)kt * 128 + gsw * 16;
    __builtin_amdgcn_global_load_lds(
        (const __attribute__((address_space(1))) void*)src,
        (__attribute__((address_space(3))) void*)(ldsB(buf) + row0 * 128),
        16, 0, 0);
  };

  const int rowLane = lane & 15;
  const int grpA    = lane >> 4;
  const int swzm    = lane & 7;

  bf16x8 aF[4][2];
  bf16x8 bF0[2], bF1[2];
  f32x4  accC[8][2];
#pragma unroll
  for (int m = 0; m < 8; ++m)
#pragma unroll
    for (int n = 0; n < 2; ++n) accC[m][n] = (f32x4){0.f, 0.f, 0.f, 0.f};

  auto readA = [&](int buf, int rh) {
    const char* base = ldsA(buf) + (wr * 128 + rh * 64 + rowLane) * 128;
#pragma unroll
    for (int m = 0; m < 4; ++m)
#pragma unroll
      for (int ks = 0; ks < 2; ++ks) {
        int g = (ks * 4 + grpA) ^ swzm;
        aF[m][ks] = *(const bf16x8*)(base + m * (16 * 128) + g * 16);
      }
  };
  auto readB = [&](int buf, int ch, bf16x8 (&dst)[2]) {
    const char* base = ldsB(buf) + (wc * WNC + ch * 16 + rowLane) * 128;
#pragma unroll
    for (int ks = 0; ks < 2; ++ks) {
      int g = (ks * 4 + grpA) ^ swzm;
      dst[ks] = *(const bf16x8*)(base + g * 16);
    }
  };

#define MFMAQ2(RH, CH, BFA)                                                   \
  do {                                                                        \
    __builtin_amdgcn_s_setprio(1);                                            \
    _Pragma("unroll")                                                         \
    for (int m_ = 0; m_ < 4; ++m_) {                                          \
      f32x4 c_ = accC[(RH) * 4 + m_][(CH)];                                   \
      c_ = __builtin_amdgcn_mfma_f32_16x16x32_bf16(aF[m_][0], BFA[0], c_, 0, 0, 0); \
      c_ = __builtin_amdgcn_mfma_f32_16x16x32_bf16(aF[m_][1], BFA[1], c_, 0, 0, 0); \
      accC[(RH) * 4 + m_][(CH)] = c_;                                         \
    }                                                                         \
    __builtin_amdgcn_s_setprio(0);                                            \
  } while (0)

  // ---- prologue: tile0 {A0,B0,A1,B1} + tile1 {A0,B0,A1}; B1(tile1) at P1.
  stageA(0, 0, 0); stageB(0, 0, 0); stageA(0, 1, 0); stageB(0, 1, 0);
  stageA(1, 0, 1); stageB(1, 0, 1); stageA(1, 1, 1);
  WAIT_VM(VN);
  BARRIER();

  for (int it = 0; it < NITER; ++it) {
    const int t0  = 2 * it;
    const int kB1 = t0 + 1;
    const int kN0 = (t0 + 2 < NT) ? t0 + 2 : NT - 1;
    const int kN1 = (t0 + 3 < NT) ? t0 + 3 : NT - 1;

    // P1
    readA(0, 0); readB(0, 0, bF0);
    stageB(1, 1, kB1);
    BARRIER(); WAIT_LGKM0();
    MFMAQ2(0, 0, bF0);
    BARRIER();
    // P2
    readB(0, 1, bF1);
    stageA(0, 0, kN0);
    BARRIER(); WAIT_LGKM0();
    MFMAQ2(0, 1, bF1);
    BARRIER();
    // P3
    readA(0, 1);
    stageB(0, 0, kN0);
    BARRIER(); WAIT_LGKM0();
    MFMAQ2(1, 1, bF1);
    BARRIER();
    // P4
    stageA(0, 1, kN0);
    WAIT_VM(VN);
    BARRIER();
    MFMAQ2(1, 0, bF0);
    BARRIER();
    // P5
    readA(1, 0); readB(1, 0, bF0);
    stageB(0, 1, kN0);
    BARRIER(); WAIT_LGKM0();
    MFMAQ2(0, 0, bF0);
    BARRIER();
    // P6
    readB(1, 1, bF1);
    stageA(1, 0, kN1);
    BARRIER(); WAIT_LGKM0();
    MFMAQ2(0, 1, bF1);
    BARRIER();
    // P7
    readA(1, 1);
    stageB(1, 0, kN1);
    BARRIER(); WAIT_LGKM0();
    MFMAQ2(1, 1, bF1);
    BARRIER();
    // P8
    stageA(1, 1, kN1);
    WAIT_VM(VN);
    BARRIER();
    MFMAQ2(1, 0, bF0);
    BARRIER();
  }
#undef MFMAQ2

  // ---- epilogue: out = float(bf16(acc))
  const int rB0 = wr * 128 + grpA * 4;
  const int cB0 = colBase + wc * WNC + rowLane;
#pragma unroll
  for (int m = 0; m < 8; ++m) {
#pragma unroll
    for (int n = 0; n < 2; ++n) {
#pragma unroll
      for (int j = 0; j < 4; ++j) {
        int r = rB0 + m * 16 + j;
        if (r < rowsValid) {
          size_t idx = (size_t)(rowBase + r) * N_DIM + (cB0 + n * 16);
          Cout[idx] = (float)(__bf16)accC[m][n][j];
        }
      }
    }
  }
}

extern "C" void kernel_launch(void* const* d_in, const int* in_sizes, int n_in,
                              void* d_out, int out_size, void* d_ws, size_t ws_size,
                              hipStream_t stream) {
  const float* x   = (const float*)d_in[0];
  const int*   cnt = (const int*)d_in[1];
  const float* wu  = (const float*)d_in[2];
  const float* wd  = (const float*)d_in[3];
  float* out = (float*)d_out;
  char*  ws  = (char*)d_ws;

  unsigned short* xb   = (unsigned short*)(ws);                // 16 MiB
  unsigned short* hbuf = (unsigned short*)(ws + (16u << 20));  // 32 MiB
  unsigned short* wdb  = (unsigned short*)(ws + (48u << 20));  // 32 MiB (w_down bf16)

  cvt_f32_bf16<<<2048, 256, 0, stream>>>(x, xb, T_TOK * D_DIM / 4);

  // GEMM1 (fused w_up cvt) + 216 co-resident w_down convert blocks
  gg1<<<dim3(40 + CVX, H_DIM / 256), dim3(512), 0, stream>>>(
      xb, wu, cnt, hbuf, wd, wdb);

  // GEMM2: clean bf16 B from wdb (round-2-proven path)
  gg2<H_DIM, D_DIM><<<dim3(40, D_DIM / 128), dim3(512), 0, stream>>>(
      hbuf, wdb, cnt, out);
}

// Round 11
// 114.300 us; speedup vs baseline: 1.4848x; 1.3144x over previous
//
#include <hip/hip_runtime.h>
#include <stdint.h>

constexpr int T_TOK = 8192;
constexpr int D_DIM = 1024;
constexpr int H_DIM = 2048;
constexpr int E_NUM = 8;

typedef __bf16 bf16x8 __attribute__((ext_vector_type(8)));
typedef float  f32x4  __attribute__((ext_vector_type(4)));
typedef unsigned int u32x4 __attribute__((ext_vector_type(4)));

static __device__ __forceinline__ unsigned short f2bf(float f) {
  union { float f; unsigned u; } a; a.f = f;
  unsigned r = a.u + 0x7fffu + ((a.u >> 16) & 1u);   // RNE
  return (unsigned short)(r >> 16);
}

// ---------------- fp32 -> bf16 conversion (x only) ----------------
__global__ void cvt_f32_bf16(const float* __restrict__ src,
                             unsigned short* __restrict__ dst, int n4) {
  int i = blockIdx.x * blockDim.x + threadIdx.x;
  int stride = gridDim.x * blockDim.x;
  for (; i < n4; i += stride) {
    float4 v = reinterpret_cast<const float4*>(src)[i];
    ushort4 o;
    o.x = f2bf(v.x); o.y = f2bf(v.y); o.z = f2bf(v.z); o.w = f2bf(v.w);
    reinterpret_cast<ushort4*>(dst)[i] = o;
  }
}

#define FENCE() asm volatile("" ::: "memory")
#define BARRIER() do { FENCE(); __builtin_amdgcn_s_barrier(); FENCE(); } while (0)
#define WAIT_LGKM0() asm volatile("s_waitcnt lgkmcnt(0)" ::: "memory")
#define WAIT_VM(N) asm volatile("s_waitcnt vmcnt(%0)" :: "i"(N) : "memory")
#define SCHED_FENCE() __builtin_amdgcn_sched_barrier(0)

static __device__ __forceinline__ f32x4 gload4(const void* p) {
  f32x4 r;
  asm volatile("global_load_dwordx4 %0, %1, off" : "=v"(r) : "v"(p) : "memory");
  return r;
}

// ---- grouped GEMM, fused B fp32->bf16 (reg-staged), deep pipeline ----
// Round-8 structure + T1 XCD swizzle: hardware XCD = linear_wg % 8; remap
// (bx,by) = (wg>>3, wg&7) so each column-block (B panel, 1 MB) is pinned to
// one XCD and the 4 row-tiles sharing it become L2-co-resident.
template <int K_DIM, int N_DIM, int BN, bool RELU2>
__global__ __launch_bounds__(512, 2)
void gg8(const unsigned short* __restrict__ A,
         const float* __restrict__ Bw,
         const int* __restrict__ counts,
         void* __restrict__ Cout) {
  constexpr int BM = 256, BK = 64;
  constexpr int NT = K_DIM / BK;
  constexpr int WNC = BN / 4;          // per-wave output cols
  constexpr int NACC = WNC / 16;       // 4 (BN=256) or 2 (BN=128)
  constexpr int NQN = NACC / 2;        // 2 or 1
  constexpr int BL = (BN == 256) ? 4 : 2;   // dwordx4 loads per B-half/thread
  constexpr int TSH = (BN == 256) ? 2 : 3;  // tid shift for B row
  constexpr int FPB = BL * 16;              // fp32 bytes per thread per half

  const int tid  = threadIdx.x;
  const int wid  = tid >> 6;
  const int lane = tid & 63;
  const int wr   = wid >> 2;
  const int wc   = wid & 3;

  // ---- XCD swizzle (bijective: grid = gridX x 8, XCD = wg % 8)
  const int wg = blockIdx.x + gridDim.x * blockIdx.y;
  const int bx = wg >> 3;
  const int by = wg & 7;

  // ---- bx -> (expert, 256-row tile)
  int t = bx;
  int e = -1, rowBase = 0, rowsValid = 0;
  {
    int tiles = 0, off = 0;
#pragma unroll
    for (int i = 0; i < E_NUM; ++i) {
      int n  = counts[i];
      int nt = (n + BM - 1) / BM;
      if (e < 0 && t < tiles + nt) {
        e = i;
        int lt = t - tiles;
        rowBase   = off + lt * BM;
        rowsValid = n - lt * BM;
        if (rowsValid > BM) rowsValid = BM;
      }
      tiles += nt; off += n;
    }
  }
  if (e < 0) return;
  const int colBase = by * BN;

  __shared__ __align__(1024) char lds[(BM + BN) * BK * 2 * 2];  // 128/96 KiB
  auto ldsA = [&](int b) -> char* { return lds + b * (BM * 128); };
  auto ldsB = [&](int b) -> char* { return lds + 2 * (BM * 128) + b * (BN * 128); };

  const char* gA = (const char*)A + (size_t)rowBase * (K_DIM * 2);
  const int  bRow0 = tid >> TSH;                        // B row within half
  const int  bByte = (tid & ((1 << TSH) - 1)) * FPB;    // byte offset in row
  const char* gBbase = (const char*)Bw +
      ((size_t)e * N_DIM + colBase) * (size_t)(K_DIM * 4);

  const int lr8 = lane >> 3;
  const int gsw = (lane & 7) ^ lr8;    // inverse-swizzled source granule (A)

  auto stageA = [&](int buf, int alpha, int kt) {
#pragma unroll
    for (int j = 0; j < 2; ++j) {
      int bi   = j * 8 + wid;
      int row0 = (bi >> 3) * 128 + alpha * 64 + (bi & 7) * 8;
      int sr   = row0 + lr8;
      if (sr >= rowsValid) sr = rowsValid - 1;
      const char* src = gA + (size_t)sr * (K_DIM * 2) + (size_t)kt * 128 + gsw * 16;
      __builtin_amdgcn_global_load_lds(
          (const __attribute__((address_space(1))) void*)src,
          (__attribute__((address_space(3))) void*)(ldsA(buf) + row0 * 128),
          16, 0, 0);
    }
  };

  auto loadBhalf = [&](f32x4 (&q)[BL], int h, int kt) {
    const char* s = gBbase + (size_t)(h * (BN / 2) + bRow0) * (K_DIM * 4)
                  + (size_t)kt * 256 + bByte;
#pragma unroll
    for (int j = 0; j < BL; ++j) q[j] = gload4(s + j * 16);
  };
  // convert (native casts -> v_cvt_pk_bf16_f32) + swizzled LDS write
  auto writeBhalf = [&](int buf, const f32x4 (&q)[BL], int h) {
    const int row = h * (BN / 2) + bRow0;
    char* base = ldsB(buf) + row * 128;
    const int rs = row & 7;
#pragma unroll
    for (int c = 0; c < BL / 2; ++c) {        // one 16B granule per 2 loads
      union { __bf16 b[8]; u32x4 w; } u;
#pragma unroll
      for (int k = 0; k < 2; ++k)
#pragma unroll
        for (int p = 0; p < 4; ++p)
          u.b[k * 4 + p] = (__bf16)q[c * 2 + k][p];
      int g = (BN == 256) ? (2 * (tid & 3) + c) : (tid & 7);
      *reinterpret_cast<u32x4*>(base + (g ^ rs) * 16) = u.w;
    }
  };

  const int rowLane = lane & 15;
  const int grpA    = lane >> 4;
  const int swzm    = lane & 7;

  bf16x8 aF[4][2];
  f32x4  accC[8][NACC];
#pragma unroll
  for (int m = 0; m < 8; ++m)
#pragma unroll
    for (int n = 0; n < NACC; ++n) accC[m][n] = (f32x4){0.f, 0.f, 0.f, 0.f};

  auto readA = [&](int buf, int rh) {
    const char* base = ldsA(buf) + (wr * 128 + rh * 64 + rowLane) * 128;
#pragma unroll
    for (int m = 0; m < 4; ++m)
#pragma unroll
      for (int ks = 0; ks < 2; ++ks) {
        int g = (ks * 4 + grpA) ^ swzm;
        aF[m][ks] = *(const bf16x8*)(base + m * (16 * 128) + g * 16);
      }
  };

  f32x4 bq0[BL], bq1[BL];

  // ---- prologue: tile0 -> buf0; leave tile1 B loads in flight (2BL)
  loadBhalf(bq0, 0, 0);
  loadBhalf(bq1, 1, 0);
  stageA(0, 0, 0); stageA(0, 1, 0);
  WAIT_VM(BL + 4); SCHED_FENCE();
  writeBhalf(0, bq0, 0);
  loadBhalf(bq0, 0, 1);
  WAIT_VM(BL + 4); SCHED_FENCE();
  writeBhalf(0, bq1, 1);
  loadBhalf(bq1, 1, 1);
  WAIT_VM(2 * BL);
  WAIT_LGKM0();
  BARRIER();

  if constexpr (BN == 256) {
    // ---------------- 4-phase schedule (GEMM1) ----------------
    bf16x8 bF0[NQN][2], bF1[NQN][2];
    auto readB = [&](int buf, int ch, bf16x8 (&dst)[NQN][2]) {
      const char* base = ldsB(buf) + (wc * WNC + ch * (WNC / 2) + rowLane) * 128;
#pragma unroll
      for (int n = 0; n < NQN; ++n)
#pragma unroll
        for (int ks = 0; ks < 2; ++ks) {
          int g = (ks * 4 + grpA) ^ swzm;
          dst[n][ks] = *(const bf16x8*)(base + n * (16 * 128) + g * 16);
        }
    };
#define MFMAQ(RH, CH, BFA)                                                    \
  do {                                                                        \
    __builtin_amdgcn_s_setprio(1);                                            \
    _Pragma("unroll")                                                         \
    for (int m_ = 0; m_ < 4; ++m_) {                                          \
      _Pragma("unroll")                                                       \
      for (int n_ = 0; n_ < NQN; ++n_) {                                      \
        f32x4 c_ = accC[(RH) * 4 + m_][(CH) * NQN + n_];                      \
        c_ = __builtin_amdgcn_mfma_f32_16x16x32_bf16(aF[m_][0], BFA[n_][0], c_, 0, 0, 0); \
        c_ = __builtin_amdgcn_mfma_f32_16x16x32_bf16(aF[m_][1], BFA[n_][1], c_, 0, 0, 0); \
        accC[(RH) * 4 + m_][(CH) * NQN + n_] = c_;                            \
      }                                                                       \
    }                                                                         \
    __builtin_amdgcn_s_setprio(0);                                            \
  } while (0)
    for (int t2 = 0; t2 < NT; ++t2) {
      const int cur = t2 & 1, nxt = cur ^ 1;
      const int ktn  = (t2 + 1 < NT) ? t2 + 1 : NT - 1;
      const int ktn2 = (t2 + 2 < NT) ? t2 + 2 : NT - 1;

      // P1
      stageA(nxt, 0, ktn);
      stageA(nxt, 1, ktn);
      readA(cur, 0); readB(cur, 0, bF0);
      BARRIER(); WAIT_LGKM0();
      MFMAQ(0, 0, bF0);
      BARRIER();
      // P2
      readB(cur, 1, bF1);
      BARRIER(); WAIT_LGKM0();
      MFMAQ(0, 1, bF1);
      BARRIER();
      // P3
      WAIT_VM(BL + 4);
      SCHED_FENCE();
      writeBhalf(nxt, bq0, 0);
      loadBhalf(bq0, 0, ktn2);
      readA(cur, 1);
      BARRIER(); WAIT_LGKM0();
      MFMAQ(1, 1, bF1);
      BARRIER();
      // P4
      WAIT_VM(BL + 4);
      SCHED_FENCE();
      writeBhalf(nxt, bq1, 1);
      loadBhalf(bq1, 1, ktn2);
      WAIT_VM(2 * BL);
      BARRIER(); WAIT_LGKM0();
      MFMAQ(1, 0, bF0);
      BARRIER();
    }
#undef MFMAQ
  } else {
    // ---------------- merged 2-phase schedule (GEMM2, BN=128) ----------------
    bf16x8 bFall[NACC][2];
    auto readBall = [&](int buf) {
      const char* base = ldsB(buf) + (wc * WNC + rowLane) * 128;
#pragma unroll
      for (int n = 0; n < NACC; ++n)
#pragma unroll
        for (int ks = 0; ks < 2; ++ks) {
          int g = (ks * 4 + grpA) ^ swzm;
          bFall[n][ks] = *(const bf16x8*)(base + n * (16 * 128) + g * 16);
        }
    };
#define MFMAQ2(RH)                                                            \
  do {                                                                        \
    __builtin_amdgcn_s_setprio(1);                                            \
    _Pragma("unroll")                                                         \
    for (int m_ = 0; m_ < 4; ++m_) {                                          \
      _Pragma("unroll")                                                       \
      for (int n_ = 0; n_ < NACC; ++n_) {                                     \
        f32x4 c_ = accC[(RH) * 4 + m_][n_];                                   \
        c_ = __builtin_amdgcn_mfma_f32_16x16x32_bf16(aF[m_][0], bFall[n_][0], c_, 0, 0, 0); \
        c_ = __builtin_amdgcn_mfma_f32_16x16x32_bf16(aF[m_][1], bFall[n_][1], c_, 0, 0, 0); \
        accC[(RH) * 4 + m_][n_] = c_;                                         \
      }                                                                       \
    }                                                                         \
    __builtin_amdgcn_s_setprio(0);                                            \
  } while (0)
    for (int t2 = 0; t2 < NT; ++t2) {
      const int cur = t2 & 1, nxt = cur ^ 1;
      const int ktn  = (t2 + 1 < NT) ? t2 + 1 : NT - 1;
      const int ktn2 = (t2 + 2 < NT) ? t2 + 2 : NT - 1;

      // P1
      stageA(nxt, 0, ktn);
      stageA(nxt, 1, ktn);
      WAIT_VM(6);
      SCHED_FENCE();
      writeBhalf(nxt, bq0, 0);
      loadBhalf(bq0, 0, ktn2);
      readA(cur, 0); readBall(cur);
      BARRIER(); WAIT_LGKM0();
      MFMAQ2(0);
      BARRIER();
      // P2
      WAIT_VM(6);
      SCHED_FENCE();
      writeBhalf(nxt, bq1, 1);
      loadBhalf(bq1, 1, ktn2);
      readA(cur, 1);
      WAIT_VM(4);
      BARRIER(); WAIT_LGKM0();
      MFMAQ2(1);
      BARRIER();
    }
#undef MFMAQ2
  }

  // ---- drain never-consumed reloads; keep dest regs alive (r6 lesson)
  WAIT_VM(0);
  SCHED_FENCE();
#pragma unroll
  for (int j = 0; j < BL; ++j) {
    asm volatile("" :: "v"(bq0[j]), "v"(bq1[j]));
  }

  // ---- epilogue. C/D: col = lane&15, row = (lane>>4)*4 + j
  const int rB0 = wr * 128 + grpA * 4;
  const int cB0 = colBase + wc * WNC + rowLane;
#pragma unroll
  for (int m = 0; m < 8; ++m) {
#pragma unroll
    for (int n = 0; n < NACC; ++n) {
#pragma unroll
      for (int j = 0; j < 4; ++j) {
        int r = rB0 + m * 16 + j;
        if (r < rowsValid) {
          size_t idx = (size_t)(rowBase + r) * N_DIM + (cB0 + n * 16);
          float v = accC[m][n][j];
          if (RELU2) {
            float rl = v > 0.f ? v : 0.f;
            float hf = (float)(__bf16)rl;              // bf16(relu(acc))
            ((__bf16*)Cout)[idx] = (__bf16)(hf * hf);  // bf16 square
          } else {
            ((float*)Cout)[idx] = (float)(__bf16)v;    // float(bf16(acc))
          }
        }
      }
    }
  }
}

extern "C" void kernel_launch(void* const* d_in, const int* in_sizes, int n_in,
                              void* d_out, int out_size, void* d_ws, size_t ws_size,
                              hipStream_t stream) {
  const float* x   = (const float*)d_in[0];
  const int*   cnt = (const int*)d_in[1];
  const float* wu  = (const float*)d_in[2];
  const float* wd  = (const float*)d_in[3];
  float* out = (float*)d_out;
  char*  ws  = (char*)d_ws;

  unsigned short* xb   = (unsigned short*)(ws);                // 16 MiB
  unsigned short* hbuf = (unsigned short*)(ws + (16u << 20));  // 32 MiB

  cvt_f32_bf16<<<2048, 256, 0, stream>>>(x, xb, T_TOK * D_DIM / 4);

  // grid.x = max tiles: floor(T/256) + E = 40 (excess blocks exit early)
  gg8<D_DIM, H_DIM, 256, true ><<<dim3(40, H_DIM / 256), dim3(512), 0, stream>>>(
      xb, wu, cnt, (void*)hbuf);
  gg8<H_DIM, D_DIM, 128, false><<<dim3(40, D_DIM / 128), dim3(512), 0, stream>>>(
      hbuf, wd, cnt, (void*)out);
}